// Round 9
// baseline (485.682 us; speedup 1.0000x reference)
//
#include <hip/hip_runtime.h>
#include <math.h>

// Problem constants
#define NB 2048            // batch
#define ZD 2048            // z dim = 2*512 + 1024, also D_H
#define SD 512             // state dim
#define NELEM_Z (NB * ZD)  // 4194304
#define MB_ (1024 * 1024)

typedef float f32x4 __attribute__((ext_vector_type(4)));
typedef __bf16 bf16x8 __attribute__((ext_vector_type(8)));
typedef __bf16 bf16x4 __attribute__((ext_vector_type(4)));
typedef long long i64;

__device__ __forceinline__ float softplus_f(float x) {
  if (x > 20.f) return x;
  if (x < -20.f) return expf(x);
  return log1pf(expf(x));
}

__device__ __forceinline__ void gload_lds16(const __bf16* g, __bf16* l) {
  __builtin_amdgcn_global_load_lds(
      (__attribute__((address_space(1))) void*)(g),
      (__attribute__((address_space(3))) void*)(l), 16, 0, 0);
}

// pack 4 floats -> 4 fp8 e4m3 bytes (OCP on gfx950)
__device__ __forceinline__ int pack_fp8x4(float a, float b, float c, float d) {
  int p = __builtin_amdgcn_cvt_pk_fp8_f32(a, b, 0, false);
  p = __builtin_amdgcn_cvt_pk_fp8_f32(c, d, p, true);
  return p;
}
__device__ __forceinline__ float fp8_to_f32(unsigned char b) {
  return __builtin_amdgcn_cvt_f32_fp8((int)b, 0);
}

// ---------------------------------------------------------------------------
// Build z = [q,p,x] (f32 + bf16 + fp8 mirrors) AND the VQC encoder angles
// fused: one block per batch row; 4 waves reduce the 2048-elem dot products.
// ---------------------------------------------------------------------------
__global__ __launch_bounds__(256) void build_z_kernel(
    const float* __restrict__ x,
    const float* __restrict__ h_padded,
    const float* __restrict__ enc_W,  // (2048,6)
    const float* __restrict__ enc_b,  // (6,)
    float* __restrict__ z,
    __bf16* __restrict__ zb,
    unsigned char* __restrict__ zf8,
    float* __restrict__ angles,       // (2048,6)
    float* __restrict__ acc) {
  int b = blockIdx.x;
  int tid = threadIdx.x;
  if (b == 0 && tid == 0) acc[0] = 0.f;
  int lane = tid & 63, w = tid >> 6;
  __shared__ float red[4][6];

  float pa[6] = {0.f, 0.f, 0.f, 0.f, 0.f, 0.f};
#pragma unroll
  for (int cc = 0; cc < 2; cc++) {
    int c = cc * 256 + tid;  // f32x4 chunk 0..511 within the row
    int i = c * 4;           // element index in z-row
    f32x4 v = (i < 1024) ? ((const f32x4*)(h_padded + (size_t)b * 2048))[c]
                         : ((const f32x4*)(x + (size_t)b * 1024))[c - 256];
    size_t zi = (size_t)b * 512 + c;
    ((f32x4*)z)[zi] = v;
    bf16x4 o;
    o[0] = (__bf16)v[0]; o[1] = (__bf16)v[1];
    o[2] = (__bf16)v[2]; o[3] = (__bf16)v[3];
    ((bf16x4*)zb)[zi] = o;
    ((int*)zf8)[zi] = pack_fp8x4(v[0], v[1], v[2], v[3]);
    int cj = (i < 1024) ? (1024 + i) : (i - 1024);  // ctrl index of v[0]
#pragma unroll
    for (int e = 0; e < 4; e++) {
      const float* wp = enc_W + (size_t)(cj + e) * 6;
#pragma unroll
      for (int k = 0; k < 6; k++) pa[k] += v[e] * wp[k];
    }
  }
#pragma unroll
  for (int k = 0; k < 6; k++)
    for (int off = 32; off > 0; off >>= 1) pa[k] += __shfl_down(pa[k], off, 64);
  if (lane == 0) {
#pragma unroll
    for (int k = 0; k < 6; k++) red[w][k] = pa[k];
  }
  __syncthreads();
  if (tid < 6)
    angles[b * 6 + tid] =
        red[0][tid] + red[1][tid] + red[2][tid] + red[3][tid] + enc_b[tid];
}

// ---------------------------------------------------------------------------
// bf16 weight prep (for W_out): f32 (R x C) -> transposed bf16 (C x R)
// ---------------------------------------------------------------------------
__global__ void prep_w(const float* __restrict__ in,
                       __bf16* __restrict__ outT, int R, int C) {
  __shared__ float tile[32][33];
  int bx = blockIdx.x * 32, by = blockIdx.y * 32;
  int tx = threadIdx.x, ty = threadIdx.y;
  for (int r = ty; r < 32; r += 8)
    tile[r][tx] = in[(size_t)(by + r) * C + bx + tx];
  __syncthreads();
  for (int r = ty; r < 32; r += 8)
    outT[(size_t)(bx + r) * R + by + tx] = (__bf16)tile[tx][r];
}

// ---------------------------------------------------------------------------
// fp8 weight prep: f32 (R x C) -> straight fp8 and transposed fp8, x16 scale.
// ---------------------------------------------------------------------------
__global__ void prep_w8(const float* __restrict__ in,
                        unsigned char* __restrict__ outN,
                        unsigned char* __restrict__ outT, int R, int C) {
  __shared__ float tile[32][33];
  int bx = blockIdx.x * 32, by = blockIdx.y * 32;
  int tx = threadIdx.x, ty = threadIdx.y;
  for (int r = ty; r < 32; r += 8) {
    float v = in[(size_t)(by + r) * C + bx + tx] * 16.f;
    tile[r][tx] = v;
    int p = __builtin_amdgcn_cvt_pk_fp8_f32(v, v, 0, false);
    outN[(size_t)(by + r) * C + bx + tx] = (unsigned char)(p & 0xff);
  }
  __syncthreads();
  for (int r = ty; r < 32; r += 8) {
    float v = tile[tx][r];
    int p = __builtin_amdgcn_cvt_pk_fp8_f32(v, v, 0, false);
    outT[(size_t)(bx + r) * R + by + tx] = (unsigned char)(p & 0xff);
  }
}

// ---------------------------------------------------------------------------
// Statevector sim: one batch row per lane, 64 amplitudes in registers.
// ---------------------------------------------------------------------------
__global__ __launch_bounds__(64) void sim_kernel(
    const float* __restrict__ angles,  // (2048,6)
    const float* __restrict__ thetas,  // (3,6)
    const float* __restrict__ gain,
    const float* __restrict__ shift,
    float* __restrict__ acc) {
  int row = blockIdx.x * 64 + threadIdx.x;
  const float* a = angles + row * 6;

  float s[64];
#pragma unroll
  for (int i = 0; i < 64; i++) s[i] = 0.f;
  s[0] = 1.f;

#pragma unroll
  for (int k = 0; k < 6; k++) {
    float half = 0.5f * a[k];
    float c = cosf(half), si = sinf(half);
    int m = 1 << (5 - k);
#pragma unroll
    for (int i = 0; i < 64; i++) {
      if ((i & m) == 0) {
        float a0 = s[i], a1 = s[i | m];
        s[i] = c * a0 - si * a1;
        s[i | m] = si * a0 + c * a1;
      }
    }
  }
#pragma unroll
  for (int l = 0; l < 3; l++) {
#pragma unroll
    for (int k = 0; k < 6; k++) {
      float half = 0.5f * thetas[l * 6 + k];
      float c = cosf(half), si = sinf(half);
      int m = 1 << (5 - k);
#pragma unroll
      for (int i = 0; i < 64; i++) {
        if ((i & m) == 0) {
          float a0 = s[i], a1 = s[i | m];
          s[i] = c * a0 - si * a1;
          s[i | m] = si * a0 + c * a1;
        }
      }
    }
#pragma unroll
    for (int i = 0; i < 64; i++) {
      int rot = ((i << 1) | (i >> 5)) & 63;
      if (__popc(i & rot) & 1) s[i] = -s[i];
    }
  }

  float val = 0.f;
#pragma unroll
  for (int i = 0; i < 64; i++) {
    float zo = (6.f - 2.f * (float)__popc(i)) * (1.f / 6.f);
    val += s[i] * s[i] * zo;
  }
  float sg = softplus_f(gain[0]);
  float ss = softplus_f(shift[0]);
  float adj = softplus_f(sg * val - ss);
  for (int off = 32; off > 0; off >>= 1) adj += __shfl_down(adj, off, 64);
  if (threadIdx.x == 0) atomicAdd(acc, adj);
}

// ---------------------------------------------------------------------------
// dt scalar chain
// ---------------------------------------------------------------------------
__global__ void dt_kernel(const float* __restrict__ acc,
                          const float* __restrict__ cap_param,
                          const float* __restrict__ time_bias,
                          const float* __restrict__ last_stable,
                          float* __restrict__ dt_out) {
  float raw = acc[0] * (1.f / (float)NB) + time_bias[0];
  float cap = fmaxf(softplus_f(cap_param[0]), 1e-6f);
  float evo = cap / (1.f + expf(-raw / cap));
  if (!isfinite(evo)) evo = cap / (1.f + expf(-time_bias[0] / cap));
  float prev = fmaxf(last_stable[0], 1e-6f);
  float cand = fmaxf(evo, 1e-6f);
  float max_step = fmaxf(prev * 0.1f, 1e-4f);
  cand = fminf(cand, prev + max_step);
  cand = fminf(cand, 0.05f);
  dt_out[0] = isfinite(cand) ? cand : prev;
}

// ---------------------------------------------------------------------------
// fp8 MFMA GEMM v3: C = epi(A[M,K] @ Bt[N,K]^T)
// Block 128x64, 128 thr = 2 waves stacked on rows; WAVE-TILE 64x64 =
// 4x4 of 16x16x32 fp8 MFMA (acc 64 VGPR). Halves LDS-read bytes per FLOP
// vs the 64x32 tile (16 b128 per 4.2 MFLOP) and doubles the per-barrier
// MFMA phase (64 MFMA ~ 310 cyc/wave) -> LDS ~1330 = MFMA ~1242 cyc/CU-iter.
// BK=128, VGPR-staged dbuf (54 KiB LDS -> 2 blocks/CU, grid 512): global->
// VGPR loads issued at iter top, MFMA phase, then ds_write (vmcnt wait lands
// post-MFMA), one lgkm-only barrier per iter.
// LDS layout: row stride 144B; k-byte kb=(h*32+q*8+b) stored at
// pos = q*32 + (h>>1)*16 + (h&1)*8 + b  -> one ds_read_b128 at
// (row*144 + q*32 + H*16) yields fragments for h=2H,2H+1; uniform banks.
// Scales: weights x16 (EPI folds 1/16); g2 carries x32.
// EPI: 0 f32 partial (split-K) | 1 fp8 tanh(v/16+bias)
//      2 fp8 32*(1-t^2)*w3[col] | 3 fp8 (v/16)*(1-h^2)
// ---------------------------------------------------------------------------
template <int EPI>
__global__ __launch_bounds__(128, 2) void mfma_gemm8(
    const unsigned char* __restrict__ A, int lda,
    const unsigned char* __restrict__ Bt, int ldb,
    void* __restrict__ Cv, int ldc,
    const float* __restrict__ bias,
    const float* __restrict__ w3,
    const unsigned char* __restrict__ aux, int ldaux,
    int Kslice) {
  __shared__ __align__(16) unsigned char sA[2][128 * 144];
  __shared__ __align__(16) unsigned char sB[2][64 * 144];

  const int tid = threadIdx.x;       // 0..127
  const int lane = tid & 63;
  const int w = tid >> 6;            // 0..1 (row half)
  const int row0 = blockIdx.y * 128;
  const int col0 = blockIdx.x * 64;
  const int koff = blockIdx.z * Kslice;

  // staging: A 8 chunks (16B), B 4 chunks per thread per BK=128 tile
  const unsigned char* gA[8]; int wA0[8], wA1[8];
  const unsigned char* gB[4]; int wB0[4], wB1[4];
#pragma unroll
  for (int i = 0; i < 8; i++) {
    int c = i * 128 + tid;           // 0..1023
    int m = c >> 3, cp = c & 7;
    gA[i] = A + (size_t)(row0 + m) * lda + koff + cp * 16;
    int h = cp >> 1;
    int Hofs = (h >> 1) * 16 + (h & 1) * 8;
    wA0[i] = m * 144 + ((2 * cp) & 3) * 32 + Hofs;
    wA1[i] = m * 144 + ((2 * cp + 1) & 3) * 32 + Hofs;
  }
#pragma unroll
  for (int i = 0; i < 4; i++) {
    int c = i * 128 + tid;           // 0..511
    int m = c >> 3, cp = c & 7;
    gB[i] = Bt + (size_t)(col0 + m) * ldb + koff + cp * 16;
    int h = cp >> 1;
    int Hofs = (h >> 1) * 16 + (h & 1) * 8;
    wB0[i] = m * 144 + ((2 * cp) & 3) * 32 + Hofs;
    wB1[i] = m * 144 + ((2 * cp + 1) & 3) * 32 + Hofs;
  }

  // fragment read offsets (b128 covers h=2H and h=2H+1)
  const int q = lane >> 4, r = lane & 15;
  int aoff[4][2], boff[4][2];
#pragma unroll
  for (int i = 0; i < 4; i++) {
    int ma = w * 64 + i * 16 + r;
#pragma unroll
    for (int H = 0; H < 2; H++) aoff[i][H] = ma * 144 + q * 32 + H * 16;
  }
#pragma unroll
  for (int j = 0; j < 4; j++) {
    int mb = j * 16 + r;
#pragma unroll
    for (int H = 0; H < 2; H++) boff[j][H] = mb * 144 + q * 32 + H * 16;
  }

  f32x4 acc[4][4] = {};
  f32x4 rA[8], rB[4];

  // tile 0: global -> regs -> LDS buf0
#pragma unroll
  for (int i = 0; i < 8; i++) rA[i] = *(const f32x4*)gA[i];
#pragma unroll
  for (int i = 0; i < 4; i++) rB[i] = *(const f32x4*)gB[i];
#pragma unroll
  for (int i = 0; i < 8; i++) {
    *(i64*)(&sA[0][0] + wA0[i]) = ((const i64*)&rA[i])[0];
    *(i64*)(&sA[0][0] + wA1[i]) = ((const i64*)&rA[i])[1];
  }
#pragma unroll
  for (int i = 0; i < 4; i++) {
    *(i64*)(&sB[0][0] + wB0[i]) = ((const i64*)&rB[i])[0];
    *(i64*)(&sB[0][0] + wB1[i]) = ((const i64*)&rB[i])[1];
  }
  __syncthreads();

  int cur = 0;
  for (int k0 = 0; k0 < Kslice; k0 += 128) {
    const bool more = (k0 + 128 < Kslice);
    if (more) {  // next-tile loads: covered by the MFMA phase below
#pragma unroll
      for (int i = 0; i < 8; i++) rA[i] = *(const f32x4*)(gA[i] + k0 + 128);
#pragma unroll
      for (int i = 0; i < 4; i++) rB[i] = *(const f32x4*)(gB[i] + k0 + 128);
    }

    const unsigned char* bA = &sA[cur][0];
    const unsigned char* bB = &sB[cur][0];
#pragma unroll
    for (int H = 0; H < 2; H++) {
      i64 a0[4], a1[4], b0[4], b1[4];
#pragma unroll
      for (int i = 0; i < 4; i++) {
        f32x4 v = *(const f32x4*)(bA + aoff[i][H]);
        a0[i] = ((const i64*)&v)[0];
        a1[i] = ((const i64*)&v)[1];
      }
#pragma unroll
      for (int j = 0; j < 4; j++) {
        f32x4 v = *(const f32x4*)(bB + boff[j][H]);
        b0[j] = ((const i64*)&v)[0];
        b1[j] = ((const i64*)&v)[1];
      }
#pragma unroll
      for (int i = 0; i < 4; i++)
#pragma unroll
        for (int j = 0; j < 4; j++)
          acc[i][j] = __builtin_amdgcn_mfma_f32_16x16x32_fp8_fp8(
              a0[i], b0[j], acc[i][j], 0, 0, 0);
#pragma unroll
      for (int i = 0; i < 4; i++)
#pragma unroll
        for (int j = 0; j < 4; j++)
          acc[i][j] = __builtin_amdgcn_mfma_f32_16x16x32_fp8_fp8(
              a1[i], b1[j], acc[i][j], 0, 0, 0);
    }

    if (more) {  // ds_write next tile (vmcnt wait lands here, post-MFMA)
      unsigned char* nA = &sA[cur ^ 1][0];
      unsigned char* nB = &sB[cur ^ 1][0];
#pragma unroll
      for (int i = 0; i < 8; i++) {
        *(i64*)(nA + wA0[i]) = ((const i64*)&rA[i])[0];
        *(i64*)(nA + wA1[i]) = ((const i64*)&rA[i])[1];
      }
#pragma unroll
      for (int i = 0; i < 4; i++) {
        *(i64*)(nB + wB0[i]) = ((const i64*)&rB[i])[0];
        *(i64*)(nB + wB1[i]) = ((const i64*)&rB[i])[1];
      }
    }
    __syncthreads();
    cur ^= 1;
  }

  // epilogue: C/D layout col=lane&15, row=(lane>>4)*4+reg
  float* Cf = (float*)Cv;
  unsigned char* C8 = (unsigned char*)Cv;
  float* Pz = Cf + (size_t)blockIdx.z * (size_t)gridDim.y * 128 * ldc;

#pragma unroll
  for (int i = 0; i < 4; i++) {
    int rowb = row0 + w * 64 + i * 16 + q * 4;
#pragma unroll
    for (int j = 0; j < 4; j++) {
      int col = col0 + j * 16 + r;
      if (EPI == 0) {
#pragma unroll
        for (int g = 0; g < 4; g++)
          Pz[(size_t)(rowb + g) * ldc + col] = acc[i][j][g];
      } else {
        float o[4];
#pragma unroll
        for (int g = 0; g < 4; g++) {
          float v = acc[i][j][g] * 0.0625f;  // undo weight x16
          if (EPI == 1) {
            o[g] = tanhf(v + bias[col]);
          } else if (EPI == 2) {
            float t = tanhf(v + bias[col]);
            o[g] = 32.f * (1.f - t * t) * w3[col];
          } else {
            float h = fp8_to_f32(aux[(size_t)(rowb + g) * ldaux + col]);
            o[g] = v * (1.f - h * h);
          }
        }
        int p = pack_fp8x4(o[0], o[1], o[2], o[3]);
#pragma unroll
        for (int g = 0; g < 4; g++)
          C8[(size_t)(rowb + g) * ldc + col] =
              (unsigned char)((p >> (8 * g)) & 0xff);
      }
    }
  }
}

// ---------------------------------------------------------------------------
// bf16 MFMA GEMM (W_out only, precision-critical): f32 split-K partials.
// ---------------------------------------------------------------------------
__global__ __launch_bounds__(256, 2) void mfma_gemm_bf16(
    const __bf16* __restrict__ A, int lda,
    const __bf16* __restrict__ Bt, int ldb,
    float* __restrict__ P, int ldc,
    int Kslice) {
  __shared__ __bf16 sA[2][128 * 64];
  __shared__ __bf16 sB[2][64 * 64];

  const int tid = threadIdx.x;
  const int lane = tid & 63;
  const int w = tid >> 6;
  const int wm = w & 1, wn = w >> 1;
  const int row0 = blockIdx.y * 128;
  const int col0 = blockIdx.x * 64;
  const int koff = blockIdx.z * Kslice;

  const __bf16* gA[4]; int lofA[4];
  const __bf16* gB[2]; int lofB[2];
#pragma unroll
  for (int i = 0; i < 4; i++) {
    int c = i * 256 + tid;
    int m = c >> 3, cc = c & 7;
    int o = cc ^ (m & 7);
    gA[i] = A + (size_t)(row0 + m) * lda + koff + o * 8;
    lofA[i] = c * 8;
  }
#pragma unroll
  for (int i = 0; i < 2; i++) {
    int c = i * 256 + tid;
    int m = c >> 3, cc = c & 7;
    int o = cc ^ (m & 7);
    gB[i] = Bt + (size_t)(col0 + m) * ldb + koff + o * 8;
    lofB[i] = c * 8;
  }

  const int q = lane >> 4, r = lane & 15;
  int aoff[4][2], boff[2][2];
#pragma unroll
  for (int i = 0; i < 4; i++) {
    int ma = wm * 64 + i * 16 + r;
#pragma unroll
    for (int h = 0; h < 2; h++)
      aoff[i][h] = (ma * 8 + ((h * 4 + q) ^ (ma & 7))) * 8;
  }
#pragma unroll
  for (int j = 0; j < 2; j++) {
    int mb = wn * 32 + j * 16 + r;
#pragma unroll
    for (int h = 0; h < 2; h++)
      boff[j][h] = (mb * 8 + ((h * 4 + q) ^ (mb & 7))) * 8;
  }

  f32x4 acc[4][2] = {};

#pragma unroll
  for (int i = 0; i < 4; i++) gload_lds16(gA[i], &sA[0][0] + lofA[i]);
#pragma unroll
  for (int i = 0; i < 2; i++) gload_lds16(gB[i], &sB[0][0] + lofB[i]);

  int cur = 0;
  for (int k0 = 0; k0 < Kslice; k0 += 64) {
    __syncthreads();
    if (k0 + 64 < Kslice) {
      int nxt = cur ^ 1;
#pragma unroll
      for (int i = 0; i < 4; i++)
        gload_lds16(gA[i] + k0 + 64, &sA[nxt][0] + lofA[i]);
#pragma unroll
      for (int i = 0; i < 2; i++)
        gload_lds16(gB[i] + k0 + 64, &sB[nxt][0] + lofB[i]);
    }
#pragma unroll
    for (int h = 0; h < 2; h++) {
      bf16x8 af[4], bfr[2];
#pragma unroll
      for (int i = 0; i < 4; i++)
        af[i] = *(const bf16x8*)(&sA[cur][0] + aoff[i][h]);
#pragma unroll
      for (int j = 0; j < 2; j++)
        bfr[j] = *(const bf16x8*)(&sB[cur][0] + boff[j][h]);
#pragma unroll
      for (int i = 0; i < 4; i++)
#pragma unroll
        for (int j = 0; j < 2; j++)
          acc[i][j] = __builtin_amdgcn_mfma_f32_16x16x32_bf16(af[i], bfr[j],
                                                              acc[i][j], 0, 0, 0);
    }
    cur ^= 1;
  }

  float* Pz = P + (size_t)blockIdx.z * (size_t)gridDim.y * 128 * ldc;
#pragma unroll
  for (int i = 0; i < 4; i++) {
    int rowb = row0 + wm * 64 + i * 16 + q * 4;
#pragma unroll
    for (int j = 0; j < 2; j++) {
      int col = col0 + wn * 32 + j * 16 + r;
#pragma unroll
      for (int g = 0; g < 4; g++)
        Pz[(size_t)(rowb + g) * ldc + col] = acc[i][j][g];
    }
  }
}

// ---------------------------------------------------------------------------
// grad = sum of 4 split-K partials (scaled 1/512 for fp8 scales);
// z[:, off:off+512] += coef*dt*grad ; refresh zb (bf16) and zf8 (fp8).
// ---------------------------------------------------------------------------
__global__ void update_kernel(float* __restrict__ z, __bf16* __restrict__ zb,
                              unsigned char* __restrict__ zf8,
                              const float* __restrict__ gp,
                              const float* __restrict__ dt,
                              float coef, int off) {
  int t = blockIdx.x * blockDim.x + threadIdx.x;  // 0 .. NB*SD/4
  int b = t >> 7;
  int j4 = t & 127;
  const f32x4* g4 = (const f32x4*)gp;
  constexpr int STRIDE = NB * SD / 4;
  f32x4 g = g4[t] + g4[t + STRIDE] + g4[t + 2 * STRIDE] + g4[t + 3 * STRIDE];
  int zi4 = (b * ZD + off) / 4 + j4;
  f32x4 v = ((f32x4*)z)[zi4];
  float s = coef * dt[0] * (1.f / 512.f);  // undo x16(w) * x32(g1)
  v[0] += s * g[0]; v[1] += s * g[1]; v[2] += s * g[2]; v[3] += s * g[3];
  ((f32x4*)z)[zi4] = v;
  bf16x4 o;
  o[0] = (__bf16)v[0]; o[1] = (__bf16)v[1];
  o[2] = (__bf16)v[2]; o[3] = (__bf16)v[3];
  ((bf16x4*)zb)[zi4] = o;
  ((int*)zf8)[zi4] = pack_fp8x4(v[0], v[1], v[2], v[3]);
}

// ---------------------------------------------------------------------------
// W_out split-K=2 reduce + bias (f32, x4 vec)
// ---------------------------------------------------------------------------
__global__ void wout_reduce(const float* __restrict__ gp,
                            const float* __restrict__ b_out,
                            float* __restrict__ out) {
  int t = blockIdx.x * blockDim.x + threadIdx.x;  // 0 .. NB*1024/4
  constexpr int S = NB * 1024 / 4;
  const f32x4* g4 = (const f32x4*)gp;
  f32x4 v = g4[t] + g4[t + S];
  f32x4 bb = ((const f32x4*)b_out)[t & 255];
  v[0] += bb[0]; v[1] += bb[1]; v[2] += bb[2]; v[3] += bb[3];
  ((f32x4*)out)[t] = v;
}

// ---------------------------------------------------------------------------
// h_next: first 8 slices = z[:, :1024] (exact f32), rest zero
// ---------------------------------------------------------------------------
__global__ void hnext_kernel(const float* __restrict__ z,
                             float* __restrict__ out) {
  int t = blockIdx.x * blockDim.x + threadIdx.x;
  int i4 = t & 511;
  f32x4 zero = {0.f, 0.f, 0.f, 0.f};
  ((f32x4*)out)[t] = (i4 < 256) ? ((const f32x4*)z)[t] : zero;
}

// ---------------------------------------------------------------------------
extern "C" void kernel_launch(void* const* d_in, const int* in_sizes, int n_in,
                              void* d_out, int out_size, void* d_ws,
                              size_t ws_size, hipStream_t stream) {
  const float* x        = (const float*)d_in[0];
  const float* h_padded = (const float*)d_in[1];
  const float* W1    = (const float*)d_in[3];
  const float* b1    = (const float*)d_in[4];
  const float* W2    = (const float*)d_in[5];
  const float* b2    = (const float*)d_in[6];
  const float* W3    = (const float*)d_in[7];
  const float* W_out = (const float*)d_in[9];
  const float* b_out = (const float*)d_in[10];
  const float* enc_W = (const float*)d_in[11];
  const float* enc_b = (const float*)d_in[12];
  const float* thetas = (const float*)d_in[13];
  const float* gain   = (const float*)d_in[14];
  const float* shift  = (const float*)d_in[15];
  const float* cap_p  = (const float*)d_in[16];
  const float* t_bias = (const float*)d_in[17];
  const float* l_stab = (const float*)d_in[18];

  float* out_mat  = (float*)d_out;              // (2048,1024)
  float* out_hnxt = (float*)d_out + NB * 1024;  // (2048,16,128)

  // workspace layout (bytes)
  char* base = (char*)d_ws;
  float* z      = (float*)(base);                      // 16MB f32
  float* part   = (float*)(base + 16 * MB_);           // 16MB f32 partials
  __bf16* zb    = (__bf16*)(base + 32 * MB_);          // 8MB bf16
  __bf16* Wot   = (__bf16*)(base + 40 * MB_);          // 2MB bf16
  float* angl   = (float*)(base + 42 * MB_);           // 48KB
  float* accp   = (float*)(base + 42 * MB_ + 65536);   // scalars
  float* dtp    = accp + 1;
  unsigned char* zf8  = (unsigned char*)(base + 43 * MB_);  // 4MB each:
  unsigned char* h1_8 = zf8 + (size_t)NELEM_Z;
  unsigned char* g2_8 = h1_8 + (size_t)NELEM_Z;
  unsigned char* g1_8 = g2_8 + (size_t)NELEM_Z;
  unsigned char* W1n8 = g1_8 + (size_t)NELEM_Z;
  unsigned char* W1t8 = W1n8 + (size_t)NELEM_Z;
  unsigned char* W2n8 = W1t8 + (size_t)NELEM_Z;
  unsigned char* W2t8 = W2n8 + (size_t)NELEM_Z;

  dim3 thr256(256);
  dim3 thr128(128);
  dim3 thrT(32, 8);

  // 1. weight prep: fp8 (straight + transposed, x16) and bf16 W_out^T
  prep_w8<<<dim3(64, 64), thrT, 0, stream>>>(W1, W1n8, W1t8, ZD, ZD);
  prep_w8<<<dim3(64, 64), thrT, 0, stream>>>(W2, W2n8, W2t8, ZD, ZD);
  prep_w<<<dim3(32, 32), thrT, 0, stream>>>(W_out, Wot, 1024, 1024);

  // 2. build z (f32/bf16/fp8) + angles, fused; then sim + dt
  build_z_kernel<<<dim3(NB), thr256, 0, stream>>>(x, h_padded, enc_W, enc_b, z,
                                                  zb, zf8, angl, accp);
  sim_kernel<<<dim3(NB / 64), dim3(64), 0, stream>>>(angl, thetas, gain, shift,
                                                     accp);
  dt_kernel<<<dim3(1), dim3(1), 0, stream>>>(accp, cap_p, t_bias, l_stab, dtp);

  // 3. three leapfrog gradient evaluations (all-fp8 grad path)
  const int   j0r[3]  = {0, 512, 0};
  const int   offs[3] = {512, 0, 512};
  const float coef[3] = {-0.5f, 1.0f, -0.5f};

  dim3 gridSq(32, 16, 1);   // 2048x2048, 128x64 tiles -> 512 blocks (2/CU)
  dim3 gridGr(8, 16, 4);    // 2048x512, split-K=4     -> 512 blocks

  for (int i = 0; i < 3; i++) {
    // h1 = tanh(z @ W1 + b1)                       (fp8 out)
    mfma_gemm8<1><<<gridSq, thr128, 0, stream>>>(
        zf8, ZD, W1t8, ZD, h1_8, ZD, b1, nullptr, nullptr, 0, ZD);
    // g2 = 32*(1 - tanh(h1 @ W2 + b2)^2) * W3[col] (fp8 out)
    mfma_gemm8<2><<<gridSq, thr128, 0, stream>>>(
        h1_8, ZD, W2t8, ZD, g2_8, ZD, b2, W3, nullptr, 0, ZD);
    // g1 = (g2 @ W2^T)/16 * (1 - h1^2)             (fp8 out, carries x32)
    mfma_gemm8<3><<<gridSq, thr128, 0, stream>>>(
        g2_8, ZD, W2n8, ZD, g1_8, ZD, nullptr, nullptr, h1_8, ZD, ZD);
    // part = g1 @ W1[j0:j0+512,:]^T  (f32 partials, split-K=4)
    mfma_gemm8<0><<<gridGr, thr128, 0, stream>>>(
        g1_8, ZD, W1n8 + (size_t)j0r[i] * ZD, ZD, part, SD, nullptr, nullptr,
        nullptr, 0, 512);
    // z[:, offs] += coef*dt*sum(part)/512
    update_kernel<<<dim3(NB * SD / 4 / 256), thr256, 0, stream>>>(
        z, zb, zf8, part, dtp, coef[i], offs[i]);
  }

  // 4. out = z[:, :1024] @ W_out + b_out  (bf16, split-K=2 + reduce)
  mfma_gemm_bf16<<<dim3(16, 16, 2), thr256, 0, stream>>>(zb, ZD, Wot, 1024,
                                                         part, 1024, 512);
  wout_reduce<<<dim3(NB * 1024 / 4 / 256), thr256, 0, stream>>>(part, b_out,
                                                                out_mat);

  // 5. h_next writeback
  hnext_kernel<<<dim3(NELEM_Z / 4 / 256), thr256, 0, stream>>>(z, out_hnxt);
}